// Round 4
// baseline (3556.940 us; speedup 1.0000x reference)
//
#include <hip/hip_runtime.h>
#include <cstdint>
#include <cstddef>

// ---------------------------------------------------------------------------
// EnhancedRNN (attention LSTM captioner). B=64, L=196, FEAT=512, T=32,
// H=512, D=512, V=32000.
//
// Round 4: runtime input-dtype detection (fp32 vs bf16) — three NaN rounds
// implicate bit-reinterpretation of d_in, i.e. inputs are likely fp32 per the
// reference's declared dtype. A detect kernel writes a device flag; all
// input-reading kernels branch (wave-uniform) on it. Output dtype = input
// float dtype. Internal scratch stays bf16 (MFMA) / fp32 (gates, state).
// Scratch lives in d_out (dead before final fc GEMM); d_ws holds hs + flag.
// ---------------------------------------------------------------------------

typedef unsigned short u16;
typedef short  s16x8  __attribute__((ext_vector_type(8)));
typedef __bf16 bf16x8 __attribute__((ext_vector_type(8)));
typedef float  f32x4  __attribute__((ext_vector_type(4)));

__device__ __forceinline__ float bf2f(u16 u) {
  union { unsigned int i; float f; } x; x.i = ((unsigned int)u) << 16; return x.f;
}
__device__ __forceinline__ u16 f2bf(float f) {
  union { float f; unsigned int i; } x; x.f = f;
  unsigned int u = x.i;
  return (u16)((u + 0x7fffu + ((u >> 16) & 1u)) >> 16);   // RNE
}
__device__ __forceinline__ float fsig(float x) { return 1.f / (1.f + __expf(-x)); }
__device__ __forceinline__ float ftanh(float x) { float e = __expf(2.f * x); return 1.f - 2.f / (e + 1.f); }

__device__ __forceinline__ bf16x8 lds_frag(const u16* p) {
  s16x8 r = *(const s16x8*)p;
  return __builtin_bit_cast(bf16x8, r);
}

// flag-aware scalar load (input tensors may be fp32 or bf16)
__device__ __forceinline__ float ldf(const void* p, size_t idx, int f32) {
  return f32 ? ((const float*)p)[idx] : bf2f(((const u16*)p)[idx]);
}
// flag-aware 8-element load -> bf16 bits (for LDS staging)
__device__ __forceinline__ s16x8 ld8(const void* p, size_t idx, int f32) {
  if (f32) {
    f32x4 a = *(const f32x4*)((const float*)p + idx);
    f32x4 b = *(const f32x4*)((const float*)p + idx + 4);
    s16x8 r;
    r[0] = (short)f2bf(a[0]); r[1] = (short)f2bf(a[1]);
    r[2] = (short)f2bf(a[2]); r[3] = (short)f2bf(a[3]);
    r[4] = (short)f2bf(b[0]); r[5] = (short)f2bf(b[1]);
    r[6] = (short)f2bf(b[2]); r[7] = (short)f2bf(b[3]);
    return r;
  }
  return *(const s16x8*)((const u16*)p + idx);
}

// ---------------------------------------------------------------------------
// Dtype detect: sample 1024 u32 words of `embedding` (~N(0,0.02), no zeros).
// If data is bf16, the low 16 bits are a bf16 with exponent in ~[114,124];
// if fp32, bits 7..14 are uniform mantissa bits (~14% in-range). Majority
// vote -> flag (1 = fp32, 0 = bf16).
// ---------------------------------------------------------------------------
__global__ void detect_kernel(const unsigned int* __restrict__ w, int* __restrict__ flagp) {
  __shared__ int votes[256];
  int v = 0;
#pragma unroll
  for (int i = 0; i < 4; ++i) {
    unsigned int x = w[threadIdx.x * 4 + i];
    int e = (x >> 7) & 0xFF;
    v += (e >= 100 && e <= 135) ? 1 : 0;
  }
  votes[threadIdx.x] = v;
  __syncthreads();
  for (int s = 128; s; s >>= 1) {
    if (threadIdx.x < s) votes[threadIdx.x] += votes[threadIdx.x + s];
    __syncthreads();
  }
  if (threadIdx.x == 0) flagp[0] = (votes[0] < 512) ? 1 : 0;
}

// ---------------------------------------------------------------------------
// bt-GEMM: C[m,n] = sum_k A[m,k]*B[n,k] + bias[n].
// A:[M,K], B:[N,K] row-major. M,N multiples of 128, K of 64.
// grid = (N/128, M/128), block = 256. Register staging, plain LDS layout.
// Modes (a/b/bias/out): 0 = bf16 fixed, 1 = f32 fixed, 2 = flag-dependent.
// ---------------------------------------------------------------------------
__global__ __launch_bounds__(256, 2) void gemm_bt(const void* __restrict__ A,
                                                  const void* __restrict__ Bm,
                                                  const void* __restrict__ bias,
                                                  void* __restrict__ Cout,
                                                  int N, int K,
                                                  const int* __restrict__ flagp,
                                                  int aMode, int bMode,
                                                  int biasMode, int outMode) {
  const int fg = flagp ? flagp[0] : 0;
  const int af32 = (aMode == 1) || (aMode == 2 && fg);
  const int bf32 = (bMode == 1) || (bMode == 2 && fg);
  const int biasf32 = (biasMode == 1) || (biasMode == 2 && fg);
  const int of32 = (outMode == 1) || (outMode == 2 && fg);

  __shared__ __align__(16) u16 As[128 * 64];
  __shared__ __align__(16) u16 Bs[128 * 64];
  const int tid = threadIdx.x;
  const int w = tid >> 6, lane = tid & 63;
  const int lm = lane & 15, quad = lane >> 4;
  const int tm0 = blockIdx.y * 128, tn0 = blockIdx.x * 128;
  const int wm = (w >> 1) * 64, wn = (w & 1) * 64;
  const int srow = tid >> 3, schunk = tid & 7;   // 32 rows x 8 chunks per pass

  f32x4 acc[4][4] = {};

  for (int kt = 0; kt < K; kt += 64) {
    s16x8 ra[4], rb[4];
#pragma unroll
    for (int i = 0; i < 4; ++i) {
      int r = i * 32 + srow;
      ra[i] = ld8(A, (size_t)(tm0 + r) * K + kt + schunk * 8, af32);
      rb[i] = ld8(Bm, (size_t)(tn0 + r) * K + kt + schunk * 8, bf32);
    }
    __syncthreads();                      // prior iteration's LDS reads done
#pragma unroll
    for (int i = 0; i < 4; ++i) {
      int r = i * 32 + srow;
      *(s16x8*)(As + r * 64 + schunk * 8) = ra[i];
      *(s16x8*)(Bs + r * 64 + schunk * 8) = rb[i];
    }
    __syncthreads();
#pragma unroll
    for (int ks = 0; ks < 2; ++ks) {
      bf16x8 af[4], bfr[4];
#pragma unroll
      for (int mi = 0; mi < 4; ++mi)
        af[mi] = lds_frag(&As[(wm + mi * 16 + lm) * 64 + (ks * 4 + quad) * 8]);
#pragma unroll
      for (int ni = 0; ni < 4; ++ni)
        bfr[ni] = lds_frag(&Bs[(wn + ni * 16 + lm) * 64 + (ks * 4 + quad) * 8]);
#pragma unroll
      for (int mi = 0; mi < 4; ++mi)
#pragma unroll
        for (int ni = 0; ni < 4; ++ni)
          acc[mi][ni] = __builtin_amdgcn_mfma_f32_16x16x32_bf16(af[mi], bfr[ni], acc[mi][ni], 0, 0, 0);
    }
  }

#pragma unroll
  for (int mi = 0; mi < 4; ++mi)
#pragma unroll
    for (int ni = 0; ni < 4; ++ni) {
      int col = tn0 + wn + ni * 16 + lm;
      float bv = ldf(bias, col, biasf32);
#pragma unroll
      for (int r = 0; r < 4; ++r) {
        int row = tm0 + wm + mi * 16 + quad * 4 + r;   // C/D: col=lane&15, row=quad*4+reg
        float v = acc[mi][ni][r] + bv;
        if (of32) ((float*)Cout)[(size_t)row * N + col] = v;
        else      ((u16*)Cout)[(size_t)row * N + col] = f2bf(v);
      }
    }
}

// ---------------------------------------------------------------------------
// Pack/precompute: gate-interleaved weight packing (jp = k*4 + gate), combined
// LSTM bias, emb gather. All converted to internal bf16 / fp32.
// ---------------------------------------------------------------------------
__global__ void pack_kernel(const int* __restrict__ caps, const void* __restrict__ embed,
                            const void* __restrict__ Wih, const void* __restrict__ Whh,
                            const void* __restrict__ bih, const void* __restrict__ bhh,
                            u16* __restrict__ WiheP, u16* __restrict__ W2p,
                            float* __restrict__ bias2, u16* __restrict__ embA,
                            const int* __restrict__ flagp) {
  const int fg = flagp[0];
  const int total = 4196352;
  for (int idx = blockIdx.x * blockDim.x + threadIdx.x; idx < total; idx += gridDim.x * blockDim.x) {
    if (idx < 1048576) {                       // WiheP[2048][512] (emb half of W_ih)
      int jp = idx >> 9, kk = idx & 511;
      int j = (jp & 3) * 512 + (jp >> 2);      // jp = k*4+gate -> torch row j = gate*512+k
      WiheP[idx] = f2bf(ldf(Wih, (size_t)j * 1024 + kk, fg));
    } else if (idx < 3145728) {                // W2p[2048][1024] = [Wih_ctx | Whh]
      int q = idx - 1048576;
      int jp = q >> 10, kk = q & 1023;
      int j = (jp & 3) * 512 + (jp >> 2);
      float v = (kk < 512) ? ldf(Wih, (size_t)j * 1024 + 512 + kk, fg)
                           : ldf(Whh, (size_t)j * 512 + (kk - 512), fg);
      W2p[q] = f2bf(v);
    } else if (idx < 3147776) {                // bias2 (packed order)
      int jp = idx - 3145728;
      int j = (jp & 3) * 512 + (jp >> 2);
      bias2[jp] = ldf(bih, j, fg) + ldf(bhh, j, fg);
    } else {                                   // embA[2048][512], row m = b*32+t
      int q = idx - 3147776;
      int m = q >> 9, kk = q & 511;
      embA[q] = f2bf(ldf(embed, (size_t)caps[m] * 512 + kk, fg));
    }
  }
}

// init: ctx0 = mean_l(enc) into xcat0 ctx-half; h-half of xcat0 = 0; c = 0.
__global__ void init_kernel(const void* __restrict__ enc, u16* __restrict__ xcat0,
                            float* __restrict__ cbuf, const int* __restrict__ flagp) {
  const int fg = flagp[0];
  int i = blockIdx.x * blockDim.x + threadIdx.x;      // 98304 threads
  if (i < 32768) {
    int b = i >> 9, f = i & 511;
    size_t base = (size_t)b * 196 * 512 + f;
    float s = 0.f;
    for (int l = 0; l < 196; ++l) s += ldf(enc, base + (size_t)l * 512, fg);
    xcat0[b * 1024 + f] = f2bf(s * (1.f / 196.f));
  } else if (i < 65536) {
    int j = i - 32768;
    int b = j >> 9, k = j & 511;
    xcat0[b * 1024 + 512 + k] = 0;                    // bf16 +0
  } else {
    cbuf[i - 65536] = 0.f;
  }
}

// ---------------------------------------------------------------------------
// Fused attention step. One block per batch element, 512 threads. encp bf16
// (internal scratch); enc/Wd/bd/vw flag-dependent.
// ---------------------------------------------------------------------------
__global__ __launch_bounds__(512) void attn_step(const void* __restrict__ enc,
                                                 const u16* __restrict__ encp,
                                                 const void* __restrict__ Wd,
                                                 const void* __restrict__ bd,
                                                 const void* __restrict__ vw,
                                                 u16* __restrict__ xcat,
                                                 const int* __restrict__ flagp) {
  const int fg = flagp[0];
  __shared__ float hb_[512], decb[512], vb_[512], sc[200], red[2];
  const int tid = threadIdx.x;
  const int b = blockIdx.x;

  hb_[tid] = bf2f(xcat[b * 1024 + 512 + tid]);
  vb_[tid] = ldf(vw, tid, fg);
  __syncthreads();

  { // dec projection: thread j -> dec[j] = bd[j] + sum_k Wd[j,k] h[k]
    float a = ldf(bd, tid, fg);
#pragma unroll 4
    for (int q = 0; q < 64; ++q) {
      s16x8 v = ld8(Wd, (size_t)tid * 512 + q * 8, fg);
#pragma unroll
      for (int j = 0; j < 8; ++j) a += bf2f((u16)v[j]) * hb_[q * 8 + j];
    }
    decb[tid] = a;
  }
  __syncthreads();

  { // scores: one wave per l row (8 waves round-robin)
    const int wv = tid >> 6, lane = tid & 63;
    for (int l = wv; l < 196; l += 8) {
      const s16x8* er = (const s16x8*)(encp + (size_t)(b * 196 + l) * 512);
      s16x8 ev = er[lane];
      float s = 0.f;
#pragma unroll
      for (int j = 0; j < 8; ++j) {
        float x = bf2f((u16)ev[j]) + decb[lane * 8 + j];
        s += vb_[lane * 8 + j] * ftanh(x);
      }
#pragma unroll
      for (int o = 32; o; o >>= 1) s += __shfl_xor(s, o, 64);
      if (lane == 0) sc[l] = s;            // v_b omitted: softmax-invariant
    }
  }
  __syncthreads();

  if (tid < 64) {
    float m = -1e30f;
    for (int l = tid; l < 196; l += 64) m = fmaxf(m, sc[l]);
#pragma unroll
    for (int o = 32; o; o >>= 1) m = fmaxf(m, __shfl_xor(m, o, 64));
    if (tid == 0) red[0] = m;
  }
  __syncthreads();
  if (tid < 196) sc[tid] = __expf(sc[tid] - red[0]);
  __syncthreads();
  if (tid < 64) {
    float s = 0.f;
    for (int l = tid; l < 196; l += 64) s += sc[l];
#pragma unroll
    for (int o = 32; o; o >>= 1) s += __shfl_xor(s, o, 64);
    if (tid == 0) red[1] = 1.f / s;
  }
  __syncthreads();

  { // context: thread f, coalesced over f per l
    float a = 0.f;
    size_t base = (size_t)b * 196 * 512 + tid;
#pragma unroll 4
    for (int l = 0; l < 196; ++l) a += sc[l] * ldf(enc, base + (size_t)l * 512, fg);
    a *= red[1];
    xcat[b * 1024 + tid] = f2bf(a);
  }
}

// ---------------------------------------------------------------------------
// Fused gates step: g = embproj[b*32+t] + [ctx|h] @ W2p.T (MFMA, M=64,
// N-tile=128), then LSTM pointwise. grid = 16 blocks, block = 256.
// All operands are internal scratch (bf16/f32) — no flag needed.
// ---------------------------------------------------------------------------
union GatesSmem {
  float f[64 * 128];      // 32 KB: gate spill
  u16   u[64 * 256];      // staging: As = u[0..4096), Bs = u[4096..12288)
};

__global__ __launch_bounds__(256, 2) void gates_step(const u16* __restrict__ xin,
                                                     u16* __restrict__ xout,
                                                     float* __restrict__ cbuf,
                                                     const u16* __restrict__ W2p,
                                                     const float* __restrict__ embproj,
                                                     u16* __restrict__ hs, int t) {
  __shared__ __align__(16) GatesSmem sm;
  u16* As = sm.u;                // 64 x 64
  u16* Bs = sm.u + 64 * 64;      // 128 x 64
  const int tid = threadIdx.x, w = tid >> 6, lane = tid & 63;
  const int lm = lane & 15, quad = lane >> 4;
  const int jb = blockIdx.x, jp0 = jb * 128;
  const int srow = tid >> 3, schunk = tid & 7;

  f32x4 acc[4][2] = {};

  for (int kt = 0; kt < 1024; kt += 64) {
    s16x8 ra[2], rb[4];
#pragma unroll
    for (int i = 0; i < 2; ++i) {
      int r = i * 32 + srow;
      ra[i] = *(const s16x8*)(xin + (size_t)r * 1024 + kt + schunk * 8);
    }
#pragma unroll
    for (int i = 0; i < 4; ++i) {
      int r = i * 32 + srow;
      rb[i] = *(const s16x8*)(W2p + (size_t)(jp0 + r) * 1024 + kt + schunk * 8);
    }
    __syncthreads();
#pragma unroll
    for (int i = 0; i < 2; ++i) {
      int r = i * 32 + srow;
      *(s16x8*)(As + r * 64 + schunk * 8) = ra[i];
    }
#pragma unroll
    for (int i = 0; i < 4; ++i) {
      int r = i * 32 + srow;
      *(s16x8*)(Bs + r * 64 + schunk * 8) = rb[i];
    }
    __syncthreads();
#pragma unroll
    for (int ks = 0; ks < 2; ++ks) {
      bf16x8 af[4], bfr[2];
#pragma unroll
      for (int mi = 0; mi < 4; ++mi)
        af[mi] = lds_frag(&As[(mi * 16 + lm) * 64 + (ks * 4 + quad) * 8]);
#pragma unroll
      for (int ni = 0; ni < 2; ++ni)
        bfr[ni] = lds_frag(&Bs[(w * 32 + ni * 16 + lm) * 64 + (ks * 4 + quad) * 8]);
#pragma unroll
      for (int mi = 0; mi < 4; ++mi)
#pragma unroll
        for (int ni = 0; ni < 2; ++ni)
          acc[mi][ni] = __builtin_amdgcn_mfma_f32_16x16x32_bf16(af[mi], bfr[ni], acc[mi][ni], 0, 0, 0);
    }
  }

  __syncthreads();   // staging reads done before spill overwrites the union
#pragma unroll
  for (int mi = 0; mi < 4; ++mi)
#pragma unroll
    for (int ni = 0; ni < 2; ++ni)
#pragma unroll
      for (int r = 0; r < 4; ++r) {
        int b = mi * 16 + quad * 4 + r;        // A-row = batch
        int jl = w * 32 + ni * 16 + lm;        // local packed gate index
        sm.f[b * 128 + jl] = acc[mi][ni][r];
      }
  __syncthreads();

  // LSTM pointwise: this block owns k in [jb*32, (jb+1)*32) for all 64 b
  for (int p = tid; p < 2048; p += 256) {
    int b = p >> 5, kl = p & 31;
    int kg = jb * 32 + kl;
    int m = b * 32 + t;
    const float* gb = &sm.f[b * 128 + kl * 4];
    const float* ep = embproj + (size_t)m * 2048 + jp0 + kl * 4;
    float gi = gb[0] + ep[0];
    float gf = gb[1] + ep[1];
    float gg = gb[2] + ep[2];
    float go = gb[3] + ep[3];
    float c0 = cbuf[b * 512 + kg];
    float c2 = fsig(gf) * c0 + fsig(gi) * ftanh(gg);
    float h2 = fsig(go) * ftanh(c2);
    cbuf[b * 512 + kg] = c2;
    u16 hb = f2bf(h2);
    xout[b * 1024 + 512 + kg] = hb;
    hs[(size_t)m * 512 + kg] = hb;
  }
}

// ---------------------------------------------------------------------------
// Scratch layout inside d_out (>=131 MB; all dead before the final fc GEMM):
// ---------------------------------------------------------------------------
static constexpr size_t OFF_ENCP = 0;                       // u16 [12544][512]
static constexpr size_t OFF_EMBP = 16777216;                // f32 [2048][2048]
static constexpr size_t OFF_EMBA = 33554432;                // u16 [2048][512]
static constexpr size_t OFF_WIHE = 35651584;                // u16 [2048][512]
static constexpr size_t OFF_W2P  = 37748736;                // u16 [2048][1024]
static constexpr size_t OFF_B2   = 41943040;                // f32 [2048]
static constexpr size_t OFF_XC0  = 41951232;                // u16 [64][1024]
static constexpr size_t OFF_XC1  = 42082304;                // u16 [64][1024]
static constexpr size_t OFF_C    = 42213376;                // f32 [64][512] -> ends 42,344,448
// d_ws: hs (u16 [2048][512] = 2 MB) + dtype flag (int).

extern "C" void kernel_launch(void* const* d_in, const int* in_sizes, int n_in,
                              void* d_out, int out_size, void* d_ws, size_t ws_size,
                              hipStream_t stream) {
  const void* enc   = d_in[0];
  const int*  caps  = (const int*)d_in[1];
  const void* embed = d_in[2];
  const void* We    = d_in[3];
  const void* be    = d_in[4];
  const void* Wd    = d_in[5];
  const void* bd    = d_in[6];
  const void* vw    = d_in[7];
  // d_in[8] (v_b) unused: constant shift inside softmax
  const void* Wih   = d_in[9];
  const void* Whh   = d_in[10];
  const void* bih   = d_in[11];
  const void* bhh   = d_in[12];
  const void* Wf    = d_in[13];
  const void* bfv   = d_in[14];

  char* ob = (char*)d_out;
  u16*   encp   = (u16*)(ob + OFF_ENCP);
  float* embp   = (float*)(ob + OFF_EMBP);
  u16*   embA   = (u16*)(ob + OFF_EMBA);
  u16*   WiheP  = (u16*)(ob + OFF_WIHE);
  u16*   W2p    = (u16*)(ob + OFF_W2P);
  float* bias2  = (float*)(ob + OFF_B2);
  u16*   xc[2]  = { (u16*)(ob + OFF_XC0), (u16*)(ob + OFF_XC1) };
  float* cbuf   = (float*)(ob + OFF_C);
  u16*   hs     = (u16*)d_ws;
  int*   flagp  = (int*)((char*)d_ws + 2048ull * 512 * 2);

  detect_kernel<<<1, 256, 0, stream>>>((const unsigned int*)embed, flagp);
  pack_kernel<<<4096, 256, 0, stream>>>(caps, embed, Wih, Whh, bih, bhh,
                                        WiheP, W2p, bias2, embA, flagp);
  init_kernel<<<384, 256, 0, stream>>>(enc, xc[0], cbuf, flagp);

  // enc_proj (bf16 scratch): [12544,512] x We[512,512] + be
  gemm_bt<<<dim3(4, 98), 256, 0, stream>>>(enc, We, be, encp, 512, 512, flagp, 2, 2, 2, 0);
  // embproj (fp32 scratch): [2048,512] x WiheP[2048,512] + (b_ih+b_hh)
  gemm_bt<<<dim3(16, 16), 256, 0, stream>>>(embA, WiheP, bias2, embp, 2048, 512, flagp, 0, 0, 1, 1);

  // step 0 (h=0, ctx = mean): gates only
  gates_step<<<16, 256, 0, stream>>>(xc[0], xc[1], cbuf, W2p, embp, hs, 0);
  // steps 1..31
  for (int t = 1; t < 32; ++t) {
    attn_step<<<64, 512, 0, stream>>>(enc, encp, Wd, bd, vw, xc[t & 1], flagp);
    gates_step<<<16, 256, 0, stream>>>(xc[t & 1], xc[(t + 1) & 1], cbuf, W2p, embp, hs, t);
  }

  // fc head: [2048,512] x Wf[32000,512] + bf -> d_out [B,T,V] (overwrites scratch)
  gemm_bt<<<dim3(250, 16), 256, 0, stream>>>(hs, Wf, bfv, d_out, 32000, 512, flagp, 0, 2, 2, 2);
}